// Round 19
// baseline (146.979 us; speedup 1.0000x reference)
//
#include <hip/hip_runtime.h>
#include <hip/hip_bf16.h>

typedef __bf16 bf16x8 __attribute__((ext_vector_type(8)));
typedef float f32x4 __attribute__((ext_vector_type(4)));
typedef float f32x16 __attribute__((ext_vector_type(16)));
typedef unsigned short u16;
typedef unsigned int u32;
typedef unsigned long long u64;
typedef u32 u32x4v __attribute__((ext_vector_type(4)));

#define QSCALE 0.18033688011112042f  /* log2(e)/8 : folds SCALE and exp->exp2 into Q */

__device__ __forceinline__ u16 f2b(float x) {
  __hip_bfloat16 h = __float2bfloat16(x);
  return __builtin_bit_cast(u16, h);
}

// HW packed f32->bf16 (RNE). Validated r14.
__device__ __forceinline__ u32 cvtpk_bf16(float a, float b) {
  u32 r;
  asm("v_cvt_pk_bf16_f32 %0, %1, %2" : "=v"(r) : "v"(a), "v"(b));
  return r;
}

__device__ __forceinline__ float max3f(float a, float b, float c) {
  float r;
  asm("v_max3_f32 %0, %1, %2, %3" : "=v"(r) : "v"(a), "v"(b), "v"(c));
  return r;
}

__device__ __forceinline__ float exp2_fast(float x) {
#if __has_builtin(__builtin_amdgcn_exp2f)
  return __builtin_amdgcn_exp2f(x);
#else
  float r; asm("v_exp_f32 %0, %1" : "=v"(r) : "v"(x)); return r;
#endif
}

// async global->LDS, 16B per lane; LDS dest = wave-uniform base + lane*16
__device__ __forceinline__ void gload_lds16(const void* g, void* l) {
  __builtin_amdgcn_global_load_lds((const __attribute__((address_space(1))) u32*)g,
                                   (__attribute__((address_space(3))) u32*)l, 16, 0, 0);
}

// ---------------- fused preprocessing: maskbits | cast | transpose Wqkv | transpose Wout ----
// (r16 known-good version; the r17/r18 bias-in-MFMA experiment failed validation twice
//  despite a symbolically-verified layout — reverted, root cause undetermined.)
__global__ __launch_bounds__(256) void prep_kernel(const float* __restrict__ x,
                                                   const int* __restrict__ mask,
                                                   const float* __restrict__ Wqkv,
                                                   const float* __restrict__ Wout,
                                                   u16* __restrict__ xb,
                                                   u64* __restrict__ mbits,
                                                   u16* __restrict__ Wqkv_t,
                                                   u16* __restrict__ Wout_t) {
  const int bid = blockIdx.x, tid = threadIdx.x;
  if (bid < 16384) {
    int gtid = bid * 256 + tid;
    int wid = gtid >> 6, lane = gtid & 63;
    int v = mask[(size_t)wid * 64 + lane];
    u64 b = __ballot(v != 0);
    if (lane == 0) mbits[wid] = b;
    return;
  }
  if (bid < 20480) {
    int i = (bid - 16384) * 256 + tid;
    float4 v = ((const float4*)x)[i];
    ushort4 o;
    o.x = f2b(v.x); o.y = f2b(v.y); o.z = f2b(v.z); o.w = f2b(v.w);
    ((ushort4*)xb)[i] = o;
    return;
  }
  __shared__ float t[32][33];
  const float* src; u16* dst; int R, C, c0, r0;
  if (bid < 23552) {
    int local = bid - 20480;            // 96 x 32 tiles
    src = Wqkv; dst = Wqkv_t; R = 1024; C = 3072;
    c0 = (local % 96) * 32; r0 = (local / 96) * 32;
  } else {
    int local = bid - 23552;            // 32 x 32 tiles
    src = Wout; dst = Wout_t; R = 1024; C = 1024;
    c0 = (local % 32) * 32; r0 = (local / 32) * 32;
  }
  const int tx = tid & 31, ty = tid >> 5;   // (32, 8)
  for (int k = 0; k < 32; k += 8)
    t[ty + k][tx] = src[(size_t)(r0 + ty + k) * C + c0 + tx];
  __syncthreads();
  for (int k = 0; k < 32; k += 8)
    dst[(size_t)(c0 + ty + k) * R + r0 + tx] = f2b(t[tx][ty + k]);
}

// ---------------- QKV GEMM: xb[4096][1024] @ Wqkv_t[3072][1024]^T ----------------
__global__ __launch_bounds__(256) void gemm_qkv_kernel(const u16* __restrict__ A,
                                                       const u16* __restrict__ Bt,
                                                       u16* __restrict__ Qb,
                                                       u16* __restrict__ Kb,
                                                       u16* __restrict__ Vt) {
  __shared__ u16 lA[128 * 32], lB[128 * 32];
  const int tid = threadIdx.x, lane = tid & 63, w = tid >> 6;
  const int wr = w >> 1, wc = w & 1, lrow = lane & 15, lk = lane >> 4;
  const int bm = blockIdx.y, bn = blockIdx.x;
  const int srow = tid >> 2, scol = (tid & 3) * 8;
  const u16* Arow = A + (size_t)(bm * 128 + srow) * 1024 + scol;
  const u16* Brow = Bt + (size_t)(bn * 128 + srow) * 1024 + scol;
  f32x4 acc[4][4] = {};
  for (int k0 = 0; k0 < 1024; k0 += 32) {
    __syncthreads();
    gload_lds16(Arow + k0,             (char*)lA + w * 1024);
    gload_lds16(Arow + 64 * 1024 + k0, (char*)lA + 4096 + w * 1024);
    gload_lds16(Brow + k0,             (char*)lB + w * 1024);
    gload_lds16(Brow + 64 * 1024 + k0, (char*)lB + 4096 + w * 1024);
    __syncthreads();
    bf16x8 af[4], bfr[4];
    for (int mi = 0; mi < 4; mi++)
      af[mi] = *(const bf16x8*)&lA[(wr * 64 + mi * 16 + lrow) * 32 + lk * 8];
    for (int ni = 0; ni < 4; ni++)
      bfr[ni] = *(const bf16x8*)&lB[(wc * 64 + ni * 16 + lrow) * 32 + lk * 8];
    for (int mi = 0; mi < 4; mi++)
      for (int ni = 0; ni < 4; ni++)
        acc[mi][ni] = __builtin_amdgcn_mfma_f32_16x16x32_bf16(af[mi], bfr[ni], acc[mi][ni], 0, 0, 0);
  }
  const int rowbase = bm * 128 + wr * 64;
  const int colbase = bn * 128 + wc * 64;
  for (int mi = 0; mi < 4; mi++)
    for (int ni = 0; ni < 4; ni++)
      for (int r = 0; r < 4; r++) {
        int row = rowbase + mi * 16 + lk * 4 + r;
        int col = colbase + ni * 16 + lrow;
        int b = row >> 11, n = row & 2047;
        int which = col >> 10, within = col & 1023;
        int h = within >> 6, d = within & 63;
        float av = acc[mi][ni][r];
        size_t bh = (size_t)(b * 16 + h);
        if (which == 0)      Qb[(bh * 2048 + n) * 64 + d] = f2b(av * QSCALE);
        else if (which == 1) Kb[(bh * 2048 + n) * 64 + d] = f2b(av);
        else                 Vt[(bh * 64 + d) * 2048 + n] = f2b(av);
      }
}

// ---------------- out-proj GEMM: attnb[4096][1024] @ Wout_t[1024][1024]^T + bias ----
__global__ __launch_bounds__(256) void gemm_out_kernel(const u16* __restrict__ A,
                                                       const u16* __restrict__ Bt,
                                                       const float* __restrict__ bias,
                                                       float* __restrict__ out) {
  __shared__ u16 lA[64 * 32], lB[128 * 32];
  const int tid = threadIdx.x, lane = tid & 63, w = tid >> 6;
  const int wr = w >> 1, wc = w & 1, lrow = lane & 15, lk = lane >> 4;
  const int bn = blockIdx.x, bm = blockIdx.y;
  const u16* Arow  = A  + (size_t)(bm * 64 + w * 16 + (lane >> 2)) * 1024 + (lane & 3) * 8;
  const u16* Brow0 = Bt + (size_t)(bn * 128 + (w * 2) * 16 + (lane >> 2)) * 1024 + (lane & 3) * 8;
  const u16* Brow1 = Brow0 + 16 * 1024;
  f32x4 acc[2][4] = {};
  for (int k0 = 0; k0 < 1024; k0 += 32) {
    __syncthreads();
    gload_lds16(Arow + k0,  (char*)lA + w * 1024);
    gload_lds16(Brow0 + k0, (char*)lB + (w * 2) * 1024);
    gload_lds16(Brow1 + k0, (char*)lB + (w * 2 + 1) * 1024);
    __syncthreads();
    bf16x8 af[2], bfr[4];
    for (int mi = 0; mi < 2; mi++)
      af[mi] = *(const bf16x8*)&lA[(wr * 32 + mi * 16 + lrow) * 32 + lk * 8];
    for (int ni = 0; ni < 4; ni++)
      bfr[ni] = *(const bf16x8*)&lB[(wc * 64 + ni * 16 + lrow) * 32 + lk * 8];
    for (int mi = 0; mi < 2; mi++)
      for (int ni = 0; ni < 4; ni++)
        acc[mi][ni] = __builtin_amdgcn_mfma_f32_16x16x32_bf16(af[mi], bfr[ni], acc[mi][ni], 0, 0, 0);
  }
  const int rowbase = bm * 64 + wr * 32;
  const int colbase = bn * 128 + wc * 64;
  for (int mi = 0; mi < 2; mi++)
    for (int ni = 0; ni < 4; ni++)
      for (int r = 0; r < 4; r++) {
        int row = rowbase + mi * 16 + lk * 4 + r;
        int col = colbase + ni * 16 + lrow;
        out[(size_t)row * 1024 + col] = acc[mi][ni][r] + bias[col];
      }
}

// ---------------- flash attention: swapped QK^T (32x32), kv-half wave split ----
// r19 = r16 (last-known-good) + kc live-range split: K frags loaded 2-at-a-time
// interleaved with their MFMAs (kc 32->16 live regs). Unified VGPR+AGPR was ~145/wave
// (3 waves/SIMD bracket); target <=128 to unlock 4 waves/SIMD. No math changes.
__global__ __launch_bounds__(256, 3) void attn_kernel(const u16* __restrict__ Qb,
                                                      const u16* __restrict__ Kb,
                                                      const u16* __restrict__ Vt,
                                                      const u64* __restrict__ Mb,
                                                      u16* __restrict__ attnb) {
  // 32KB: [0,8K) Kbuf0, [8K,16K) Kbuf1, [16K,24K) Vbuf0, [24K,32K) Vbuf1.
  // comb (f32 [2][34][64] = 17.4KB) overlays [0,17.4K) after the kv sweep.
  __shared__ u32 smem[8192];
  const int tid = threadIdx.x, lane = tid & 63, w = tid >> 6;
  const int l31 = lane & 31, hi = lane >> 5;
  const int wq = w & 1, wk = w >> 1;
  // XCD swizzle: wrk = (bid%8)*128 + bid/8  (bijective: 1024 % 8 == 0). r15: FETCH 70->14MB.
  const int wrk = ((blockIdx.x & 7) << 7) + (blockIdx.x >> 3);
  const int qt = wrk & 31, bh = wrk >> 5;
  const int h = bh & 15, b = bh >> 4;
  const int q = qt * 64 + wq * 32 + l31;
  const u16* Qp = Qb + (size_t)bh * 2048 * 64;
  const u16* Kp = Kb + (size_t)bh * 2048 * 64;
  const u16* Vp = Vt + (size_t)bh * 64 * 2048;

  // staging: wave w covers rows [16w,16w+16) of both K and V^T tiles.
  const int rsub = lane >> 3;                       // 0..7
  const int usrc = ((lane & 7) ^ rsub) * 8;         // pre-swizzled source 16B unit
  const u16* kptr  = Kp + (size_t)rsub * 64 + usrc;
  const u16* vptr0 = Vp + (size_t)(8 * (2 * w)     + rsub) * 2048 + usrc;
  const u16* vptr1 = Vp + (size_t)(8 * (2 * w + 1) + rsub) * 2048 + usrc;
  const u64* mrp = Mb + (size_t)q * 32;

  char* const kb0 = (char*)smem + (2 * w) * 1024;
  char* const vb0 = (char*)smem + 16384 + (2 * w) * 1024;

  // Q B-frags: col=q=lane&31, k-half by hi; resident whole kernel
  bf16x8 qf[4];
#pragma unroll
  for (int t = 0; t < 4; t++)
    qf[t] = *(const bf16x8*)&Qp[(size_t)q * 64 + t * 16 + hi * 8];

  f32x16 acc0 = {}, acc1 = {};  // O^T partial (this wave's kv-half): d [0,32)/[32,64), col=q
  float m_run = 5.0f, lsum = 0.f;  // max-primed (r16): rescale ~never fires, kept for safety

  // stage chunk 0 into buf 0
  {
    gload_lds16(kptr + 512 * (2 * w),     kb0);
    gload_lds16(kptr + 512 * (2 * w + 1), kb0 + 1024);
    gload_lds16(vptr0,                    vb0);
    gload_lds16(vptr1,                    vb0 + 1024);
    kptr += 4096; vptr0 += 64; vptr1 += 64;
  }
  u64 mw = *mrp++;

  auto chunk = [&](int CUR, int c) {
    __syncthreads();  // drains vmcnt: buf[CUR] staged; prior reads of buf[CUR^1] done
    if (c + 1 < 32) {
      char* kb = kb0 + (CUR ^ 1) * 8192;
      char* vb = vb0 + (CUR ^ 1) * 8192;
      gload_lds16(kptr + 512 * (2 * w),     kb);
      gload_lds16(kptr + 512 * (2 * w + 1), kb + 1024);
      gload_lds16(vptr0,                    vb);
      gload_lds16(vptr1,                    vb + 1024);
      kptr += 4096; vptr0 += 64; vptr1 += 64;
    }
    u64 mw_n = (c + 1 < 32) ? *mrp++ : 0;

    const char* Kbase = (const char*)smem + CUR * 8192;
    const char* Vbase = (const char*)smem + 16384 + CUR * 8192;
    const int krow = wk * 32 + l31;

    // S^T = K_half · Q^T over d=64; K frags loaded 2-at-a-time (kc live range halved)
    f32x16 s = {};
    bf16x8 kc0, kc1;
    kc0 = *(const bf16x8*)(Kbase + krow * 128 + (((0 * 2 + hi) ^ (l31 & 7)) * 16));
    kc1 = *(const bf16x8*)(Kbase + krow * 128 + (((1 * 2 + hi) ^ (l31 & 7)) * 16));
    __builtin_amdgcn_s_setprio(1);
    s = __builtin_amdgcn_mfma_f32_32x32x16_bf16(kc0, qf[0], s, 0, 0, 0);
    s = __builtin_amdgcn_mfma_f32_32x32x16_bf16(kc1, qf[1], s, 0, 0, 0);
    __builtin_amdgcn_s_setprio(0);
    kc0 = *(const bf16x8*)(Kbase + krow * 128 + (((2 * 2 + hi) ^ (l31 & 7)) * 16));
    kc1 = *(const bf16x8*)(Kbase + krow * 128 + (((3 * 2 + hi) ^ (l31 & 7)) * 16));
    __builtin_amdgcn_s_setprio(1);
    s = __builtin_amdgcn_mfma_f32_32x32x16_bf16(kc0, qf[2], s, 0, 0, 0);
    s = __builtin_amdgcn_mfma_f32_32x32x16_bf16(kc1, qf[3], s, 0, 0, 0);
    __builtin_amdgcn_s_setprio(0);

    // raw row-max over the half (mask applied later by zeroing p), max3 tree + partner
    float mx[8];
#pragma unroll
    for (int i = 0; i < 8; i++) mx[i] = fmaxf(s[i], s[i + 8]);
    float pm = fmaxf(max3f(mx[0], mx[1], mx[2]),
                     fmaxf(max3f(mx[3], mx[4], mx[5]), fmaxf(mx[6], mx[7])));
    pm = fmaxf(pm, __shfl_xor(pm, 32, 64));

    // deferred rescale (THR=8 in log2 domain -> p bounded by 256); ~never fires
    if (__any(pm > m_run + 8.f)) {
      float mn = fmaxf(m_run, pm);
      float fs = exp2_fast(m_run - mn);
      m_run = mn;
      lsum *= fs;
      acc0 *= fs;
      acc1 *= fs;
    }

    // p = exp2(s - m), mask-zero (this wave's 32-bit mask half), pack via HW cvt_pk
    u32 msel = wk ? (u32)(mw >> 32) : (u32)mw;
    u32 wsh = msel >> (4 * hi);
    u32 wwd[8];
#pragma unroll
    for (int p = 0; p < 8; p++) {
      const int r0 = 2 * p;
      const int sh = (r0 & 3) + 8 * (p >> 1);  // kv_local - 4*hi for reg r0
      float a0 = exp2_fast(s[r0] - m_run);
      float a1 = exp2_fast(s[r0 + 1] - m_run);
      a0 = ((wsh >> sh) & 1u) ? a0 : 0.f;
      a1 = ((wsh >> (sh + 1)) & 1u) ? a1 : 0.f;
      lsum += a0 + a1;
      wwd[p] = cvtpk_bf16(a0, a1);
    }

    // V frags for this wave's kv-half (on-demand: short live range)
    bf16x8 va[2][2];
#pragma unroll
    for (int dt = 0; dt < 2; dt++)
#pragma unroll
      for (int kk = 0; kk < 2; kk++) {
        const int row = dt * 32 + l31;
        const int u = (wk * 4 + kk * 2 + hi) ^ (l31 & 7);
        va[dt][kk] = *(const bf16x8*)(Vbase + row * 128 + u * 16);
      }

    // PV: B-frags via in-register half-exchange (validated r9/r10), kk over 2 k-slices
    __builtin_amdgcn_s_setprio(1);
#pragma unroll
    for (int kk = 0; kk < 2; kk++) {
      const int b4 = kk * 4;
      u32 a0w = wwd[b4 + 0], a1w = wwd[b4 + 1], a2w = wwd[b4 + 2], a3w = wwd[b4 + 3];
      u32 e0 = __shfl_xor(hi ? a0w : a2w, 32, 64);
      u32 e1 = __shfl_xor(hi ? a1w : a3w, 32, 64);
      u32 f0 = hi ? e0 : a0w;
      u32 f1 = hi ? e1 : a1w;
      u32 f2c = hi ? a2w : e0;
      u32 f3 = hi ? a3w : e1;
      u32x4v pv4 = {f0, f1, f2c, f3};
      bf16x8 pbf = __builtin_bit_cast(bf16x8, pv4);
      acc0 = __builtin_amdgcn_mfma_f32_32x32x16_bf16(va[0][kk], pbf, acc0, 0, 0, 0);
      acc1 = __builtin_amdgcn_mfma_f32_32x32x16_bf16(va[1][kk], pbf, acc1, 0, 0, 0);
    }
    __builtin_amdgcn_s_setprio(0);

    mw = mw_n;
  };

  for (int c = 0; c < 32; c += 2) {
    chunk(0, c);
    chunk(1, c + 1);
  }

  // ---- in-block merge of kv-half partials (comb overlays dead K/V LDS) ----
  lsum += __shfl_xor(lsum, 32, 64);
  __syncthreads();                   // all K/V reads done before comb overwrites
  float* comb = (float*)smem;        // [2][34][64] f32 = 17.4KB
  float* cb = comb + wq * 34 * 64;
  if (wk == 1) {
    cb[0 * 64 + lane] = m_run;
    cb[1 * 64 + lane] = lsum;
#pragma unroll
    for (int r = 0; r < 16; r++) {
      cb[(2 + r) * 64 + lane]  = acc0[r];
      cb[(18 + r) * 64 + lane] = acc1[r];
    }
  }
  __syncthreads();
  if (wk == 0) {
    float mB = cb[0 * 64 + lane];
    float lB_ = cb[1 * 64 + lane];
    float mT = fmaxf(m_run, mB);
    float fA = exp2_fast(m_run - mT);
    float fB = exp2_fast(mB - mT);
    float lt = lsum * fA + lB_ * fB;
    float ia = fA / lt, ib = fB / lt;
#pragma unroll
    for (int r = 0; r < 16; r++) {
      acc0[r] = acc0[r] * ia + cb[(2 + r) * 64 + lane] * ib;
      acc1[r] = acc1[r] * ia + cb[(18 + r) * 64 + lane] * ib;
    }
    u16* orow = attnb + ((size_t)b * 2048 + q) * 1024 + h * 64;
#pragma unroll
    for (int rq = 0; rq < 4; rq++) {
      const int rb = rq * 4;
      {
        uint2 st;
        st.x = cvtpk_bf16(acc0[rb], acc0[rb + 1]);
        st.y = cvtpk_bf16(acc0[rb + 2], acc0[rb + 3]);
        *(uint2*)(orow + 8 * rq + 4 * hi) = st;
      }
      {
        uint2 st;
        st.x = cvtpk_bf16(acc1[rb], acc1[rb + 1]);
        st.y = cvtpk_bf16(acc1[rb + 2], acc1[rb + 3]);
        *(uint2*)(orow + 32 + 8 * rq + 4 * hi) = st;
      }
    }
  }
}

extern "C" void kernel_launch(void* const* d_in, const int* in_sizes, int n_in,
                              void* d_out, int out_size, void* d_ws, size_t ws_size,
                              hipStream_t stream) {
  const float* x    = (const float*)d_in[0];
  const int*   mask = (const int*)d_in[1];
  const float* Wqkv = (const float*)d_in[2];
  const float* Wout = (const float*)d_in[3];
  const float* bout = (const float*)d_in[4];
  float* out = (float*)d_out;

  char* ws = (char*)d_ws;
  // layout (bytes): [0,8M) xb / attnb; [8,14M) Wqkv_t; [14,16M) Wout_t; [16,16.5M) mbits;
  // [17,25M) Qb; [25,33M) Kb; [33,41M) Vt
  u16* xb     = (u16*)(ws);
  u16* attnb  = xb;
  u16* Wqkv_t = (u16*)(ws + (size_t)(8u << 20));
  u16* Wout_t = (u16*)(ws + (size_t)(14u << 20));
  u64* mbits  = (u64*)(ws + (size_t)(16u << 20));
  u16* Qb     = (u16*)(ws + (size_t)(17u << 20));
  u16* Kb     = (u16*)(ws + (size_t)(25u << 20));
  u16* Vt     = (u16*)(ws + (size_t)(33u << 20));

  prep_kernel<<<24576, 256, 0, stream>>>(x, mask, Wqkv, Wout, xb, mbits, Wqkv_t, Wout_t);
  gemm_qkv_kernel<<<dim3(24, 32), 256, 0, stream>>>(xb, Wqkv_t, Qb, Kb, Vt);
  attn_kernel<<<1024, 256, 0, stream>>>(Qb, Kb, Vt, mbits, attnb);
  gemm_out_kernel<<<dim3(8, 64), 256, 0, stream>>>(attnb, Wout_t, bout, out);
}

// Round 20
// 142.275 us; speedup vs baseline: 1.0331x; 1.0331x over previous
//
#include <hip/hip_runtime.h>
#include <hip/hip_bf16.h>

typedef __bf16 bf16x8 __attribute__((ext_vector_type(8)));
typedef float f32x4 __attribute__((ext_vector_type(4)));
typedef float f32x16 __attribute__((ext_vector_type(16)));
typedef unsigned short u16;
typedef unsigned int u32;
typedef unsigned long long u64;
typedef u32 u32x4v __attribute__((ext_vector_type(4)));

#define QSCALE 0.18033688011112042f  /* log2(e)/8 : folds SCALE and exp->exp2 into Q */

__device__ __forceinline__ u16 f2b(float x) {
  __hip_bfloat16 h = __float2bfloat16(x);
  return __builtin_bit_cast(u16, h);
}

// HW packed f32->bf16 (RNE). Validated r14.
__device__ __forceinline__ u32 cvtpk_bf16(float a, float b) {
  u32 r;
  asm("v_cvt_pk_bf16_f32 %0, %1, %2" : "=v"(r) : "v"(a), "v"(b));
  return r;
}

__device__ __forceinline__ float max3f(float a, float b, float c) {
  float r;
  asm("v_max3_f32 %0, %1, %2, %3" : "=v"(r) : "v"(a), "v"(b), "v"(c));
  return r;
}

__device__ __forceinline__ float exp2_fast(float x) {
#if __has_builtin(__builtin_amdgcn_exp2f)
  return __builtin_amdgcn_exp2f(x);
#else
  float r; asm("v_exp_f32 %0, %1" : "=v"(r) : "v"(x)); return r;
#endif
}

// async global->LDS, 16B per lane; LDS dest = wave-uniform base + lane*16
__device__ __forceinline__ void gload_lds16(const void* g, void* l) {
  __builtin_amdgcn_global_load_lds((const __attribute__((address_space(1))) u32*)g,
                                   (__attribute__((address_space(3))) u32*)l, 16, 0, 0);
}

// ---------------- fused preprocessing: maskbits | cast | transpose Wqkv | transpose Wout ----
__global__ __launch_bounds__(256) void prep_kernel(const float* __restrict__ x,
                                                   const int* __restrict__ mask,
                                                   const float* __restrict__ Wqkv,
                                                   const float* __restrict__ Wout,
                                                   u16* __restrict__ xb,
                                                   u64* __restrict__ mbits,
                                                   u16* __restrict__ Wqkv_t,
                                                   u16* __restrict__ Wout_t) {
  const int bid = blockIdx.x, tid = threadIdx.x;
  if (bid < 16384) {
    int gtid = bid * 256 + tid;
    int wid = gtid >> 6, lane = gtid & 63;
    int v = mask[(size_t)wid * 64 + lane];
    u64 b = __ballot(v != 0);
    if (lane == 0) mbits[wid] = b;
    return;
  }
  if (bid < 20480) {
    int i = (bid - 16384) * 256 + tid;
    float4 v = ((const float4*)x)[i];
    ushort4 o;
    o.x = f2b(v.x); o.y = f2b(v.y); o.z = f2b(v.z); o.w = f2b(v.w);
    ((ushort4*)xb)[i] = o;
    return;
  }
  __shared__ float t[32][33];
  const float* src; u16* dst; int R, C, c0, r0;
  if (bid < 23552) {
    int local = bid - 20480;            // 96 x 32 tiles
    src = Wqkv; dst = Wqkv_t; R = 1024; C = 3072;
    c0 = (local % 96) * 32; r0 = (local / 96) * 32;
  } else {
    int local = bid - 23552;            // 32 x 32 tiles
    src = Wout; dst = Wout_t; R = 1024; C = 1024;
    c0 = (local % 32) * 32; r0 = (local / 32) * 32;
  }
  const int tx = tid & 31, ty = tid >> 5;   // (32, 8)
  for (int k = 0; k < 32; k += 8)
    t[ty + k][tx] = src[(size_t)(r0 + ty + k) * C + c0 + tx];
  __syncthreads();
  for (int k = 0; k < 32; k += 8)
    dst[(size_t)(c0 + ty + k) * R + r0 + tx] = f2b(t[tx][ty + k]);
}

// ---------------- QKV GEMM: xb[4096][1024] @ Wqkv_t[3072][1024]^T ----------------
__global__ __launch_bounds__(256) void gemm_qkv_kernel(const u16* __restrict__ A,
                                                       const u16* __restrict__ Bt,
                                                       u16* __restrict__ Qb,
                                                       u16* __restrict__ Kb,
                                                       u16* __restrict__ Vt) {
  __shared__ u16 lA[128 * 32], lB[128 * 32];
  const int tid = threadIdx.x, lane = tid & 63, w = tid >> 6;
  const int wr = w >> 1, wc = w & 1, lrow = lane & 15, lk = lane >> 4;
  const int bm = blockIdx.y, bn = blockIdx.x;
  const int srow = tid >> 2, scol = (tid & 3) * 8;
  const u16* Arow = A + (size_t)(bm * 128 + srow) * 1024 + scol;
  const u16* Brow = Bt + (size_t)(bn * 128 + srow) * 1024 + scol;
  f32x4 acc[4][4] = {};
  for (int k0 = 0; k0 < 1024; k0 += 32) {
    __syncthreads();
    gload_lds16(Arow + k0,             (char*)lA + w * 1024);
    gload_lds16(Arow + 64 * 1024 + k0, (char*)lA + 4096 + w * 1024);
    gload_lds16(Brow + k0,             (char*)lB + w * 1024);
    gload_lds16(Brow + 64 * 1024 + k0, (char*)lB + 4096 + w * 1024);
    __syncthreads();
    bf16x8 af[4], bfr[4];
    for (int mi = 0; mi < 4; mi++)
      af[mi] = *(const bf16x8*)&lA[(wr * 64 + mi * 16 + lrow) * 32 + lk * 8];
    for (int ni = 0; ni < 4; ni++)
      bfr[ni] = *(const bf16x8*)&lB[(wc * 64 + ni * 16 + lrow) * 32 + lk * 8];
    for (int mi = 0; mi < 4; mi++)
      for (int ni = 0; ni < 4; ni++)
        acc[mi][ni] = __builtin_amdgcn_mfma_f32_16x16x32_bf16(af[mi], bfr[ni], acc[mi][ni], 0, 0, 0);
  }
  const int rowbase = bm * 128 + wr * 64;
  const int colbase = bn * 128 + wc * 64;
  for (int mi = 0; mi < 4; mi++)
    for (int ni = 0; ni < 4; ni++)
      for (int r = 0; r < 4; r++) {
        int row = rowbase + mi * 16 + lk * 4 + r;
        int col = colbase + ni * 16 + lrow;
        int b = row >> 11, n = row & 2047;
        int which = col >> 10, within = col & 1023;
        int h = within >> 6, d = within & 63;
        float av = acc[mi][ni][r];
        size_t bh = (size_t)(b * 16 + h);
        if (which == 0)      Qb[(bh * 2048 + n) * 64 + d] = f2b(av * QSCALE);
        else if (which == 1) Kb[(bh * 2048 + n) * 64 + d] = f2b(av);
        else                 Vt[(bh * 64 + d) * 2048 + n] = f2b(av);
      }
}

// ---------------- out-proj GEMM: attnb[4096][1024] @ Wout_t[1024][1024]^T + bias ----
__global__ __launch_bounds__(256) void gemm_out_kernel(const u16* __restrict__ A,
                                                       const u16* __restrict__ Bt,
                                                       const float* __restrict__ bias,
                                                       float* __restrict__ out) {
  __shared__ u16 lA[64 * 32], lB[128 * 32];
  const int tid = threadIdx.x, lane = tid & 63, w = tid >> 6;
  const int wr = w >> 1, wc = w & 1, lrow = lane & 15, lk = lane >> 4;
  const int bn = blockIdx.x, bm = blockIdx.y;
  const u16* Arow  = A  + (size_t)(bm * 64 + w * 16 + (lane >> 2)) * 1024 + (lane & 3) * 8;
  const u16* Brow0 = Bt + (size_t)(bn * 128 + (w * 2) * 16 + (lane >> 2)) * 1024 + (lane & 3) * 8;
  const u16* Brow1 = Brow0 + 16 * 1024;
  f32x4 acc[2][4] = {};
  for (int k0 = 0; k0 < 1024; k0 += 32) {
    __syncthreads();
    gload_lds16(Arow + k0,  (char*)lA + w * 1024);
    gload_lds16(Brow0 + k0, (char*)lB + (w * 2) * 1024);
    gload_lds16(Brow1 + k0, (char*)lB + (w * 2 + 1) * 1024);
    __syncthreads();
    bf16x8 af[2], bfr[4];
    for (int mi = 0; mi < 2; mi++)
      af[mi] = *(const bf16x8*)&lA[(wr * 32 + mi * 16 + lrow) * 32 + lk * 8];
    for (int ni = 0; ni < 4; ni++)
      bfr[ni] = *(const bf16x8*)&lB[(wc * 64 + ni * 16 + lrow) * 32 + lk * 8];
    for (int mi = 0; mi < 2; mi++)
      for (int ni = 0; ni < 4; ni++)
        acc[mi][ni] = __builtin_amdgcn_mfma_f32_16x16x32_bf16(af[mi], bfr[ni], acc[mi][ni], 0, 0, 0);
  }
  const int rowbase = bm * 64 + wr * 32;
  const int colbase = bn * 128 + wc * 64;
  for (int mi = 0; mi < 2; mi++)
    for (int ni = 0; ni < 4; ni++)
      for (int r = 0; r < 4; r++) {
        int row = rowbase + mi * 16 + lk * 4 + r;
        int col = colbase + ni * 16 + lrow;
        out[(size_t)row * 1024 + col] = acc[mi][ni][r] + bias[col];
      }
}

// ---------------- flash attention: swapped QK^T (32x32), kv-half wave split ----
// r20 = r16 verbatim (best measured: attn 71.3us, total 141.9us).
// r19's kc live-range split regressed (occ 31->24%, +7us) — reverted.
__global__ __launch_bounds__(256, 3) void attn_kernel(const u16* __restrict__ Qb,
                                                      const u16* __restrict__ Kb,
                                                      const u16* __restrict__ Vt,
                                                      const u64* __restrict__ Mb,
                                                      u16* __restrict__ attnb) {
  // 32KB: [0,8K) Kbuf0, [8K,16K) Kbuf1, [16K,24K) Vbuf0, [24K,32K) Vbuf1.
  // comb (f32 [2][34][64] = 17.4KB) overlays [0,17.4K) after the kv sweep.
  __shared__ u32 smem[8192];
  const int tid = threadIdx.x, lane = tid & 63, w = tid >> 6;
  const int l31 = lane & 31, hi = lane >> 5;
  const int wq = w & 1, wk = w >> 1;
  // XCD swizzle: wrk = (bid%8)*128 + bid/8  (bijective: 1024 % 8 == 0). r15: FETCH 70->14MB.
  const int wrk = ((blockIdx.x & 7) << 7) + (blockIdx.x >> 3);
  const int qt = wrk & 31, bh = wrk >> 5;
  const int h = bh & 15, b = bh >> 4;
  const int q = qt * 64 + wq * 32 + l31;
  const u16* Qp = Qb + (size_t)bh * 2048 * 64;
  const u16* Kp = Kb + (size_t)bh * 2048 * 64;
  const u16* Vp = Vt + (size_t)bh * 64 * 2048;

  // staging: wave w covers rows [16w,16w+16) of both K and V^T tiles.
  const int rsub = lane >> 3;                       // 0..7
  const int usrc = ((lane & 7) ^ rsub) * 8;         // pre-swizzled source 16B unit
  const u16* kptr  = Kp + (size_t)rsub * 64 + usrc;
  const u16* vptr0 = Vp + (size_t)(8 * (2 * w)     + rsub) * 2048 + usrc;
  const u16* vptr1 = Vp + (size_t)(8 * (2 * w + 1) + rsub) * 2048 + usrc;
  const u64* mrp = Mb + (size_t)q * 32;

  char* const kb0 = (char*)smem + (2 * w) * 1024;
  char* const vb0 = (char*)smem + 16384 + (2 * w) * 1024;

  // Q B-frags: col=q=lane&31, k-half by hi; resident whole kernel
  bf16x8 qf[4];
#pragma unroll
  for (int t = 0; t < 4; t++)
    qf[t] = *(const bf16x8*)&Qp[(size_t)q * 64 + t * 16 + hi * 8];

  f32x16 acc0 = {}, acc1 = {};  // O^T partial (this wave's kv-half): d [0,32)/[32,64), col=q
  float m_run = 5.0f, lsum = 0.f;  // max-primed: S log2-domain row-max ~4.7 -> rescale ~never fires

  // stage chunk 0 into buf 0
  {
    gload_lds16(kptr + 512 * (2 * w),     kb0);
    gload_lds16(kptr + 512 * (2 * w + 1), kb0 + 1024);
    gload_lds16(vptr0,                    vb0);
    gload_lds16(vptr1,                    vb0 + 1024);
    kptr += 4096; vptr0 += 64; vptr1 += 64;
  }
  u64 mw = *mrp++;

  auto chunk = [&](int CUR, int c) {
    __syncthreads();  // drains vmcnt: buf[CUR] staged; prior reads of buf[CUR^1] done
    if (c + 1 < 32) {
      char* kb = kb0 + (CUR ^ 1) * 8192;
      char* vb = vb0 + (CUR ^ 1) * 8192;
      gload_lds16(kptr + 512 * (2 * w),     kb);
      gload_lds16(kptr + 512 * (2 * w + 1), kb + 1024);
      gload_lds16(vptr0,                    vb);
      gload_lds16(vptr1,                    vb + 1024);
      kptr += 4096; vptr0 += 64; vptr1 += 64;
    }
    u64 mw_n = (c + 1 < 32) ? *mrp++ : 0;

    const char* Kbase = (const char*)smem + CUR * 8192;
    const char* Vbase = (const char*)smem + 16384 + CUR * 8192;

    // K frags for this wave's kv-half (swizzled read)
    bf16x8 kc[4];
#pragma unroll
    for (int t = 0; t < 4; t++) {
      const int row = wk * 32 + l31;
      const int u = (t * 2 + hi) ^ (l31 & 7);
      kc[t] = *(const bf16x8*)(Kbase + row * 128 + u * 16);
    }

    // S^T (one 32x32 tile) = K_half · Q^T over d=64 (log2-scaled already)
    f32x16 s = {};
    __builtin_amdgcn_s_setprio(1);
#pragma unroll
    for (int t = 0; t < 4; t++)
      s = __builtin_amdgcn_mfma_f32_32x32x16_bf16(kc[t], qf[t], s, 0, 0, 0);
    __builtin_amdgcn_s_setprio(0);

    // raw row-max over the half (mask applied later by zeroing p), max3 tree + partner
    float mx[8];
#pragma unroll
    for (int i = 0; i < 8; i++) mx[i] = fmaxf(s[i], s[i + 8]);
    float pm = fmaxf(max3f(mx[0], mx[1], mx[2]),
                     fmaxf(max3f(mx[3], mx[4], mx[5]), fmaxf(mx[6], mx[7])));
    pm = fmaxf(pm, __shfl_xor(pm, 32, 64));

    // deferred rescale (THR=8 in log2 domain -> p bounded by 256); ~never fires
    // with m_run primed at 5.0 (row-max ~4.7), kept for safety.
    if (__any(pm > m_run + 8.f)) {
      float mn = fmaxf(m_run, pm);
      float fs = exp2_fast(m_run - mn);
      m_run = mn;
      lsum *= fs;
      acc0 *= fs;
      acc1 *= fs;
    }

    // p = exp2(s - m), mask-zero (this wave's 32-bit mask half), pack via HW cvt_pk
    u32 msel = wk ? (u32)(mw >> 32) : (u32)mw;
    u32 wsh = msel >> (4 * hi);
    u32 wwd[8];
#pragma unroll
    for (int p = 0; p < 8; p++) {
      const int r0 = 2 * p;
      const int sh = (r0 & 3) + 8 * (p >> 1);  // kv_local - 4*hi for reg r0
      float a0 = exp2_fast(s[r0] - m_run);
      float a1 = exp2_fast(s[r0 + 1] - m_run);
      a0 = ((wsh >> sh) & 1u) ? a0 : 0.f;
      a1 = ((wsh >> (sh + 1)) & 1u) ? a1 : 0.f;
      lsum += a0 + a1;
      wwd[p] = cvtpk_bf16(a0, a1);
    }

    // V frags for this wave's kv-half (on-demand: short live range)
    bf16x8 va[2][2];
#pragma unroll
    for (int dt = 0; dt < 2; dt++)
#pragma unroll
      for (int kk = 0; kk < 2; kk++) {
        const int row = dt * 32 + l31;
        const int u = (wk * 4 + kk * 2 + hi) ^ (l31 & 7);
        va[dt][kk] = *(const bf16x8*)(Vbase + row * 128 + u * 16);
      }

    // PV: B-frags via in-register half-exchange (validated r9/r10), kk over 2 k-slices
    __builtin_amdgcn_s_setprio(1);
#pragma unroll
    for (int kk = 0; kk < 2; kk++) {
      const int b4 = kk * 4;
      u32 a0w = wwd[b4 + 0], a1w = wwd[b4 + 1], a2w = wwd[b4 + 2], a3w = wwd[b4 + 3];
      u32 e0 = __shfl_xor(hi ? a0w : a2w, 32, 64);
      u32 e1 = __shfl_xor(hi ? a1w : a3w, 32, 64);
      u32 f0 = hi ? e0 : a0w;
      u32 f1 = hi ? e1 : a1w;
      u32 f2c = hi ? a2w : e0;
      u32 f3 = hi ? a3w : e1;
      u32x4v pv4 = {f0, f1, f2c, f3};
      bf16x8 pbf = __builtin_bit_cast(bf16x8, pv4);
      acc0 = __builtin_amdgcn_mfma_f32_32x32x16_bf16(va[0][kk], pbf, acc0, 0, 0, 0);
      acc1 = __builtin_amdgcn_mfma_f32_32x32x16_bf16(va[1][kk], pbf, acc1, 0, 0, 0);
    }
    __builtin_amdgcn_s_setprio(0);

    mw = mw_n;
  };

  for (int c = 0; c < 32; c += 2) {
    chunk(0, c);
    chunk(1, c + 1);
  }

  // ---- in-block merge of kv-half partials (comb overlays dead K/V LDS) ----
  lsum += __shfl_xor(lsum, 32, 64);  // combine hi halves: lsum now per-q total for this half
  __syncthreads();                   // all K/V reads done before comb overwrites
  float* comb = (float*)smem;        // [2][34][64] f32 = 17.4KB
  float* cb = comb + wq * 34 * 64;
  if (wk == 1) {
    cb[0 * 64 + lane] = m_run;
    cb[1 * 64 + lane] = lsum;
#pragma unroll
    for (int r = 0; r < 16; r++) {
      cb[(2 + r) * 64 + lane]  = acc0[r];
      cb[(18 + r) * 64 + lane] = acc1[r];
    }
  }
  __syncthreads();
  if (wk == 0) {
    float mB = cb[0 * 64 + lane];
    float lB_ = cb[1 * 64 + lane];
    float mT = fmaxf(m_run, mB);
    float fA = exp2_fast(m_run - mT);
    float fB = exp2_fast(mB - mT);
    float lt = lsum * fA + lB_ * fB;
    float ia = fA / lt, ib = fB / lt;
#pragma unroll
    for (int r = 0; r < 16; r++) {
      acc0[r] = acc0[r] * ia + cb[(2 + r) * 64 + lane] * ib;
      acc1[r] = acc1[r] * ia + cb[(18 + r) * 64 + lane] * ib;
    }
    u16* orow = attnb + ((size_t)b * 2048 + q) * 1024 + h * 64;
#pragma unroll
    for (int rq = 0; rq < 4; rq++) {
      const int rb = rq * 4;
      {
        uint2 st;
        st.x = cvtpk_bf16(acc0[rb], acc0[rb + 1]);
        st.y = cvtpk_bf16(acc0[rb + 2], acc0[rb + 3]);
        *(uint2*)(orow + 8 * rq + 4 * hi) = st;
      }
      {
        uint2 st;
        st.x = cvtpk_bf16(acc1[rb], acc1[rb + 1]);
        st.y = cvtpk_bf16(acc1[rb + 2], acc1[rb + 3]);
        *(uint2*)(orow + 32 + 8 * rq + 4 * hi) = st;
      }
    }
  }
}

extern "C" void kernel_launch(void* const* d_in, const int* in_sizes, int n_in,
                              void* d_out, int out_size, void* d_ws, size_t ws_size,
                              hipStream_t stream) {
  const float* x    = (const float*)d_in[0];
  const int*   mask = (const int*)d_in[1];
  const float* Wqkv = (const float*)d_in[2];
  const float* Wout = (const float*)d_in[3];
  const float* bout = (const float*)d_in[4];
  float* out = (float*)d_out;

  char* ws = (char*)d_ws;
  // layout (bytes): [0,8M) xb / attnb; [8,14M) Wqkv_t; [14,16M) Wout_t; [16,16.5M) mbits;
  // [17,25M) Qb; [25,33M) Kb; [33,41M) Vt
  u16* xb     = (u16*)(ws);
  u16* attnb  = xb;
  u16* Wqkv_t = (u16*)(ws + (size_t)(8u << 20));
  u16* Wout_t = (u16*)(ws + (size_t)(14u << 20));
  u64* mbits  = (u64*)(ws + (size_t)(16u << 20));
  u16* Qb     = (u16*)(ws + (size_t)(17u << 20));
  u16* Kb     = (u16*)(ws + (size_t)(25u << 20));
  u16* Vt     = (u16*)(ws + (size_t)(33u << 20));

  prep_kernel<<<24576, 256, 0, stream>>>(x, mask, Wqkv, Wout, xb, mbits, Wqkv_t, Wout_t);
  gemm_qkv_kernel<<<dim3(24, 32), 256, 0, stream>>>(xb, Wqkv_t, Qb, Kb, Vt);
  attn_kernel<<<1024, 256, 0, stream>>>(Qb, Kb, Vt, mbits, attnb);
  gemm_out_kernel<<<dim3(8, 64), 256, 0, stream>>>(attnb, Wout_t, bout, out);
}

// Round 21
// 140.334 us; speedup vs baseline: 1.0474x; 1.0138x over previous
//
#include <hip/hip_runtime.h>
#include <hip/hip_bf16.h>

typedef __bf16 bf16x8 __attribute__((ext_vector_type(8)));
typedef float f32x4 __attribute__((ext_vector_type(4)));
typedef float f32x16 __attribute__((ext_vector_type(16)));
typedef unsigned short u16;
typedef unsigned int u32;
typedef unsigned long long u64;
typedef u32 u32x4v __attribute__((ext_vector_type(4)));

#define QSCALE 0.18033688011112042f  /* log2(e)/8 : folds SCALE and exp->exp2 into Q */

__device__ __forceinline__ u16 f2b(float x) {
  __hip_bfloat16 h = __float2bfloat16(x);
  return __builtin_bit_cast(u16, h);
}

// HW packed f32->bf16 (RNE). Validated r14.
__device__ __forceinline__ u32 cvtpk_bf16(float a, float b) {
  u32 r;
  asm("v_cvt_pk_bf16_f32 %0, %1, %2" : "=v"(r) : "v"(a), "v"(b));
  return r;
}

__device__ __forceinline__ float max3f(float a, float b, float c) {
  float r;
  asm("v_max3_f32 %0, %1, %2, %3" : "=v"(r) : "v"(a), "v"(b), "v"(c));
  return r;
}

__device__ __forceinline__ float exp2_fast(float x) {
#if __has_builtin(__builtin_amdgcn_exp2f)
  return __builtin_amdgcn_exp2f(x);
#else
  float r; asm("v_exp_f32 %0, %1" : "=v"(r) : "v"(x)); return r;
#endif
}

// async global->LDS, 16B per lane; LDS dest = wave-uniform base + lane*16
__device__ __forceinline__ void gload_lds16(const void* g, void* l) {
  __builtin_amdgcn_global_load_lds((const __attribute__((address_space(1))) u32*)g,
                                   (__attribute__((address_space(3))) u32*)l, 16, 0, 0);
}

// ---------------- fused preprocessing: maskbits | cast | transpose Wqkv | transpose Wout ----
__global__ __launch_bounds__(256) void prep_kernel(const float* __restrict__ x,
                                                   const int* __restrict__ mask,
                                                   const float* __restrict__ Wqkv,
                                                   const float* __restrict__ Wout,
                                                   u16* __restrict__ xb,
                                                   u64* __restrict__ mbits,
                                                   u16* __restrict__ Wqkv_t,
                                                   u16* __restrict__ Wout_t) {
  const int bid = blockIdx.x, tid = threadIdx.x;
  if (bid < 16384) {
    int gtid = bid * 256 + tid;
    int wid = gtid >> 6, lane = gtid & 63;
    int v = mask[(size_t)wid * 64 + lane];
    u64 b = __ballot(v != 0);
    if (lane == 0) mbits[wid] = b;
    return;
  }
  if (bid < 20480) {
    int i = (bid - 16384) * 256 + tid;
    float4 v = ((const float4*)x)[i];
    ushort4 o;
    o.x = f2b(v.x); o.y = f2b(v.y); o.z = f2b(v.z); o.w = f2b(v.w);
    ((ushort4*)xb)[i] = o;
    return;
  }
  __shared__ float t[32][33];
  const float* src; u16* dst; int R, C, c0, r0;
  if (bid < 23552) {
    int local = bid - 20480;            // 96 x 32 tiles
    src = Wqkv; dst = Wqkv_t; R = 1024; C = 3072;
    c0 = (local % 96) * 32; r0 = (local / 96) * 32;
  } else {
    int local = bid - 23552;            // 32 x 32 tiles
    src = Wout; dst = Wout_t; R = 1024; C = 1024;
    c0 = (local % 32) * 32; r0 = (local / 32) * 32;
  }
  const int tx = tid & 31, ty = tid >> 5;   // (32, 8)
  for (int k = 0; k < 32; k += 8)
    t[ty + k][tx] = src[(size_t)(r0 + ty + k) * C + c0 + tx];
  __syncthreads();
  for (int k = 0; k < 32; k += 8)
    dst[(size_t)(c0 + ty + k) * R + r0 + tx] = f2b(t[tx][ty + k]);
}

// ---------------- QKV GEMM: xb[4096][1024] @ Wqkv_t[3072][1024]^T ----------------
// r21: flat grid 768 + bijective XCD swizzle (768 = 8*96): each XCD owns 4 consecutive
// bm panels (A slice 1MB -> L2-resident) instead of round-robin refetching every panel.
__global__ __launch_bounds__(256) void gemm_qkv_kernel(const u16* __restrict__ A,
                                                       const u16* __restrict__ Bt,
                                                       u16* __restrict__ Qb,
                                                       u16* __restrict__ Kb,
                                                       u16* __restrict__ Vt) {
  __shared__ u16 lA[128 * 32], lB[128 * 32];
  const int tid = threadIdx.x, lane = tid & 63, w = tid >> 6;
  const int wr = w >> 1, wc = w & 1, lrow = lane & 15, lk = lane >> 4;
  const int wrk = (blockIdx.x & 7) * 96 + (blockIdx.x >> 3);
  const int bm = wrk / 24, bn = wrk % 24;
  const int srow = tid >> 2, scol = (tid & 3) * 8;
  const u16* Arow = A + (size_t)(bm * 128 + srow) * 1024 + scol;
  const u16* Brow = Bt + (size_t)(bn * 128 + srow) * 1024 + scol;
  f32x4 acc[4][4] = {};
  for (int k0 = 0; k0 < 1024; k0 += 32) {
    __syncthreads();
    gload_lds16(Arow + k0,             (char*)lA + w * 1024);
    gload_lds16(Arow + 64 * 1024 + k0, (char*)lA + 4096 + w * 1024);
    gload_lds16(Brow + k0,             (char*)lB + w * 1024);
    gload_lds16(Brow + 64 * 1024 + k0, (char*)lB + 4096 + w * 1024);
    __syncthreads();
    bf16x8 af[4], bfr[4];
    for (int mi = 0; mi < 4; mi++)
      af[mi] = *(const bf16x8*)&lA[(wr * 64 + mi * 16 + lrow) * 32 + lk * 8];
    for (int ni = 0; ni < 4; ni++)
      bfr[ni] = *(const bf16x8*)&lB[(wc * 64 + ni * 16 + lrow) * 32 + lk * 8];
    for (int mi = 0; mi < 4; mi++)
      for (int ni = 0; ni < 4; ni++)
        acc[mi][ni] = __builtin_amdgcn_mfma_f32_16x16x32_bf16(af[mi], bfr[ni], acc[mi][ni], 0, 0, 0);
  }
  const int rowbase = bm * 128 + wr * 64;
  const int colbase = bn * 128 + wc * 64;
  for (int mi = 0; mi < 4; mi++)
    for (int ni = 0; ni < 4; ni++)
      for (int r = 0; r < 4; r++) {
        int row = rowbase + mi * 16 + lk * 4 + r;
        int col = colbase + ni * 16 + lrow;
        int b = row >> 11, n = row & 2047;
        int which = col >> 10, within = col & 1023;
        int h = within >> 6, d = within & 63;
        float av = acc[mi][ni][r];
        size_t bh = (size_t)(b * 16 + h);
        if (which == 0)      Qb[(bh * 2048 + n) * 64 + d] = f2b(av * QSCALE);
        else if (which == 1) Kb[(bh * 2048 + n) * 64 + d] = f2b(av);
        else                 Vt[(bh * 64 + d) * 2048 + n] = f2b(av);
      }
}

// ---------------- out-proj GEMM: attnb[4096][1024] @ Wout_t[1024][1024]^T + bias ----
// r21: flat grid 512 + bijective XCD swizzle (512 = 8*64): XCD owns 8 consecutive bm
// panels (attnb slice 1MB L2-resident).
__global__ __launch_bounds__(256) void gemm_out_kernel(const u16* __restrict__ A,
                                                       const u16* __restrict__ Bt,
                                                       const float* __restrict__ bias,
                                                       float* __restrict__ out) {
  __shared__ u16 lA[64 * 32], lB[128 * 32];
  const int tid = threadIdx.x, lane = tid & 63, w = tid >> 6;
  const int wr = w >> 1, wc = w & 1, lrow = lane & 15, lk = lane >> 4;
  const int wrk = ((blockIdx.x & 7) << 6) + (blockIdx.x >> 3);
  const int bm = wrk >> 3, bn = wrk & 7;
  const u16* Arow  = A  + (size_t)(bm * 64 + w * 16 + (lane >> 2)) * 1024 + (lane & 3) * 8;
  const u16* Brow0 = Bt + (size_t)(bn * 128 + (w * 2) * 16 + (lane >> 2)) * 1024 + (lane & 3) * 8;
  const u16* Brow1 = Brow0 + 16 * 1024;
  f32x4 acc[2][4] = {};
  for (int k0 = 0; k0 < 1024; k0 += 32) {
    __syncthreads();
    gload_lds16(Arow + k0,  (char*)lA + w * 1024);
    gload_lds16(Brow0 + k0, (char*)lB + (w * 2) * 1024);
    gload_lds16(Brow1 + k0, (char*)lB + (w * 2 + 1) * 1024);
    __syncthreads();
    bf16x8 af[2], bfr[4];
    for (int mi = 0; mi < 2; mi++)
      af[mi] = *(const bf16x8*)&lA[(wr * 32 + mi * 16 + lrow) * 32 + lk * 8];
    for (int ni = 0; ni < 4; ni++)
      bfr[ni] = *(const bf16x8*)&lB[(wc * 64 + ni * 16 + lrow) * 32 + lk * 8];
    for (int mi = 0; mi < 2; mi++)
      for (int ni = 0; ni < 4; ni++)
        acc[mi][ni] = __builtin_amdgcn_mfma_f32_16x16x32_bf16(af[mi], bfr[ni], acc[mi][ni], 0, 0, 0);
  }
  const int rowbase = bm * 64 + wr * 32;
  const int colbase = bn * 128 + wc * 64;
  for (int mi = 0; mi < 2; mi++)
    for (int ni = 0; ni < 4; ni++)
      for (int r = 0; r < 4; r++) {
        int row = rowbase + mi * 16 + lk * 4 + r;
        int col = colbase + ni * 16 + lrow;
        out[(size_t)row * 1024 + col] = acc[mi][ni][r] + bias[col];
      }
}

// ---------------- flash attention: swapped QK^T (32x32), kv-half wave split ----
// r21 = r16/r20 verbatim (best measured: attn 71.5us). Untouched for clean attribution.
__global__ __launch_bounds__(256, 3) void attn_kernel(const u16* __restrict__ Qb,
                                                      const u16* __restrict__ Kb,
                                                      const u16* __restrict__ Vt,
                                                      const u64* __restrict__ Mb,
                                                      u16* __restrict__ attnb) {
  // 32KB: [0,8K) Kbuf0, [8K,16K) Kbuf1, [16K,24K) Vbuf0, [24K,32K) Vbuf1.
  // comb (f32 [2][34][64] = 17.4KB) overlays [0,17.4K) after the kv sweep.
  __shared__ u32 smem[8192];
  const int tid = threadIdx.x, lane = tid & 63, w = tid >> 6;
  const int l31 = lane & 31, hi = lane >> 5;
  const int wq = w & 1, wk = w >> 1;
  // XCD swizzle: wrk = (bid%8)*128 + bid/8  (bijective: 1024 % 8 == 0). r15: FETCH 70->14MB.
  const int wrk = ((blockIdx.x & 7) << 7) + (blockIdx.x >> 3);
  const int qt = wrk & 31, bh = wrk >> 5;
  const int h = bh & 15, b = bh >> 4;
  const int q = qt * 64 + wq * 32 + l31;
  const u16* Qp = Qb + (size_t)bh * 2048 * 64;
  const u16* Kp = Kb + (size_t)bh * 2048 * 64;
  const u16* Vp = Vt + (size_t)bh * 64 * 2048;

  // staging: wave w covers rows [16w,16w+16) of both K and V^T tiles.
  const int rsub = lane >> 3;                       // 0..7
  const int usrc = ((lane & 7) ^ rsub) * 8;         // pre-swizzled source 16B unit
  const u16* kptr  = Kp + (size_t)rsub * 64 + usrc;
  const u16* vptr0 = Vp + (size_t)(8 * (2 * w)     + rsub) * 2048 + usrc;
  const u16* vptr1 = Vp + (size_t)(8 * (2 * w + 1) + rsub) * 2048 + usrc;
  const u64* mrp = Mb + (size_t)q * 32;

  char* const kb0 = (char*)smem + (2 * w) * 1024;
  char* const vb0 = (char*)smem + 16384 + (2 * w) * 1024;

  // Q B-frags: col=q=lane&31, k-half by hi; resident whole kernel
  bf16x8 qf[4];
#pragma unroll
  for (int t = 0; t < 4; t++)
    qf[t] = *(const bf16x8*)&Qp[(size_t)q * 64 + t * 16 + hi * 8];

  f32x16 acc0 = {}, acc1 = {};  // O^T partial (this wave's kv-half): d [0,32)/[32,64), col=q
  float m_run = 5.0f, lsum = 0.f;  // max-primed: S log2-domain row-max ~4.7 -> rescale ~never fires

  // stage chunk 0 into buf 0
  {
    gload_lds16(kptr + 512 * (2 * w),     kb0);
    gload_lds16(kptr + 512 * (2 * w + 1), kb0 + 1024);
    gload_lds16(vptr0,                    vb0);
    gload_lds16(vptr1,                    vb0 + 1024);
    kptr += 4096; vptr0 += 64; vptr1 += 64;
  }
  u64 mw = *mrp++;

  auto chunk = [&](int CUR, int c) {
    __syncthreads();  // drains vmcnt: buf[CUR] staged; prior reads of buf[CUR^1] done
    if (c + 1 < 32) {
      char* kb = kb0 + (CUR ^ 1) * 8192;
      char* vb = vb0 + (CUR ^ 1) * 8192;
      gload_lds16(kptr + 512 * (2 * w),     kb);
      gload_lds16(kptr + 512 * (2 * w + 1), kb + 1024);
      gload_lds16(vptr0,                    vb);
      gload_lds16(vptr1,                    vb + 1024);
      kptr += 4096; vptr0 += 64; vptr1 += 64;
    }
    u64 mw_n = (c + 1 < 32) ? *mrp++ : 0;

    const char* Kbase = (const char*)smem + CUR * 8192;
    const char* Vbase = (const char*)smem + 16384 + CUR * 8192;

    // K frags for this wave's kv-half (swizzled read)
    bf16x8 kc[4];
#pragma unroll
    for (int t = 0; t < 4; t++) {
      const int row = wk * 32 + l31;
      const int u = (t * 2 + hi) ^ (l31 & 7);
      kc[t] = *(const bf16x8*)(Kbase + row * 128 + u * 16);
    }

    // S^T (one 32x32 tile) = K_half · Q^T over d=64 (log2-scaled already)
    f32x16 s = {};
    __builtin_amdgcn_s_setprio(1);
#pragma unroll
    for (int t = 0; t < 4; t++)
      s = __builtin_amdgcn_mfma_f32_32x32x16_bf16(kc[t], qf[t], s, 0, 0, 0);
    __builtin_amdgcn_s_setprio(0);

    // raw row-max over the half (mask applied later by zeroing p), max3 tree + partner
    float mx[8];
#pragma unroll
    for (int i = 0; i < 8; i++) mx[i] = fmaxf(s[i], s[i + 8]);
    float pm = fmaxf(max3f(mx[0], mx[1], mx[2]),
                     fmaxf(max3f(mx[3], mx[4], mx[5]), fmaxf(mx[6], mx[7])));
    pm = fmaxf(pm, __shfl_xor(pm, 32, 64));

    // deferred rescale (THR=8 in log2 domain -> p bounded by 256); ~never fires
    // with m_run primed at 5.0 (row-max ~4.7), kept for safety.
    if (__any(pm > m_run + 8.f)) {
      float mn = fmaxf(m_run, pm);
      float fs = exp2_fast(m_run - mn);
      m_run = mn;
      lsum *= fs;
      acc0 *= fs;
      acc1 *= fs;
    }

    // p = exp2(s - m), mask-zero (this wave's 32-bit mask half), pack via HW cvt_pk
    u32 msel = wk ? (u32)(mw >> 32) : (u32)mw;
    u32 wsh = msel >> (4 * hi);
    u32 wwd[8];
#pragma unroll
    for (int p = 0; p < 8; p++) {
      const int r0 = 2 * p;
      const int sh = (r0 & 3) + 8 * (p >> 1);  // kv_local - 4*hi for reg r0
      float a0 = exp2_fast(s[r0] - m_run);
      float a1 = exp2_fast(s[r0 + 1] - m_run);
      a0 = ((wsh >> sh) & 1u) ? a0 : 0.f;
      a1 = ((wsh >> (sh + 1)) & 1u) ? a1 : 0.f;
      lsum += a0 + a1;
      wwd[p] = cvtpk_bf16(a0, a1);
    }

    // V frags for this wave's kv-half (on-demand: short live range)
    bf16x8 va[2][2];
#pragma unroll
    for (int dt = 0; dt < 2; dt++)
#pragma unroll
      for (int kk = 0; kk < 2; kk++) {
        const int row = dt * 32 + l31;
        const int u = (wk * 4 + kk * 2 + hi) ^ (l31 & 7);
        va[dt][kk] = *(const bf16x8*)(Vbase + row * 128 + u * 16);
      }

    // PV: B-frags via in-register half-exchange (validated r9/r10), kk over 2 k-slices
    __builtin_amdgcn_s_setprio(1);
#pragma unroll
    for (int kk = 0; kk < 2; kk++) {
      const int b4 = kk * 4;
      u32 a0w = wwd[b4 + 0], a1w = wwd[b4 + 1], a2w = wwd[b4 + 2], a3w = wwd[b4 + 3];
      u32 e0 = __shfl_xor(hi ? a0w : a2w, 32, 64);
      u32 e1 = __shfl_xor(hi ? a1w : a3w, 32, 64);
      u32 f0 = hi ? e0 : a0w;
      u32 f1 = hi ? e1 : a1w;
      u32 f2c = hi ? a2w : e0;
      u32 f3 = hi ? a3w : e1;
      u32x4v pv4 = {f0, f1, f2c, f3};
      bf16x8 pbf = __builtin_bit_cast(bf16x8, pv4);
      acc0 = __builtin_amdgcn_mfma_f32_32x32x16_bf16(va[0][kk], pbf, acc0, 0, 0, 0);
      acc1 = __builtin_amdgcn_mfma_f32_32x32x16_bf16(va[1][kk], pbf, acc1, 0, 0, 0);
    }
    __builtin_amdgcn_s_setprio(0);

    mw = mw_n;
  };

  for (int c = 0; c < 32; c += 2) {
    chunk(0, c);
    chunk(1, c + 1);
  }

  // ---- in-block merge of kv-half partials (comb overlays dead K/V LDS) ----
  lsum += __shfl_xor(lsum, 32, 64);  // combine hi halves: lsum now per-q total for this half
  __syncthreads();                   // all K/V reads done before comb overwrites
  float* comb = (float*)smem;        // [2][34][64] f32 = 17.4KB
  float* cb = comb + wq * 34 * 64;
  if (wk == 1) {
    cb[0 * 64 + lane] = m_run;
    cb[1 * 64 + lane] = lsum;
#pragma unroll
    for (int r = 0; r < 16; r++) {
      cb[(2 + r) * 64 + lane]  = acc0[r];
      cb[(18 + r) * 64 + lane] = acc1[r];
    }
  }
  __syncthreads();
  if (wk == 0) {
    float mB = cb[0 * 64 + lane];
    float lB_ = cb[1 * 64 + lane];
    float mT = fmaxf(m_run, mB);
    float fA = exp2_fast(m_run - mT);
    float fB = exp2_fast(mB - mT);
    float lt = lsum * fA + lB_ * fB;
    float ia = fA / lt, ib = fB / lt;
#pragma unroll
    for (int r = 0; r < 16; r++) {
      acc0[r] = acc0[r] * ia + cb[(2 + r) * 64 + lane] * ib;
      acc1[r] = acc1[r] * ia + cb[(18 + r) * 64 + lane] * ib;
    }
    u16* orow = attnb + ((size_t)b * 2048 + q) * 1024 + h * 64;
#pragma unroll
    for (int rq = 0; rq < 4; rq++) {
      const int rb = rq * 4;
      {
        uint2 st;
        st.x = cvtpk_bf16(acc0[rb], acc0[rb + 1]);
        st.y = cvtpk_bf16(acc0[rb + 2], acc0[rb + 3]);
        *(uint2*)(orow + 8 * rq + 4 * hi) = st;
      }
      {
        uint2 st;
        st.x = cvtpk_bf16(acc1[rb], acc1[rb + 1]);
        st.y = cvtpk_bf16(acc1[rb + 2], acc1[rb + 3]);
        *(uint2*)(orow + 32 + 8 * rq + 4 * hi) = st;
      }
    }
  }
}

extern "C" void kernel_launch(void* const* d_in, const int* in_sizes, int n_in,
                              void* d_out, int out_size, void* d_ws, size_t ws_size,
                              hipStream_t stream) {
  const float* x    = (const float*)d_in[0];
  const int*   mask = (const int*)d_in[1];
  const float* Wqkv = (const float*)d_in[2];
  const float* Wout = (const float*)d_in[3];
  const float* bout = (const float*)d_in[4];
  float* out = (float*)d_out;

  char* ws = (char*)d_ws;
  // layout (bytes): [0,8M) xb / attnb; [8,14M) Wqkv_t; [14,16M) Wout_t; [16,16.5M) mbits;
  // [17,25M) Qb; [25,33M) Kb; [33,41M) Vt
  u16* xb     = (u16*)(ws);
  u16* attnb  = xb;
  u16* Wqkv_t = (u16*)(ws + (size_t)(8u << 20));
  u16* Wout_t = (u16*)(ws + (size_t)(14u << 20));
  u64* mbits  = (u64*)(ws + (size_t)(16u << 20));
  u16* Qb     = (u16*)(ws + (size_t)(17u << 20));
  u16* Kb     = (u16*)(ws + (size_t)(25u << 20));
  u16* Vt     = (u16*)(ws + (size_t)(33u << 20));

  prep_kernel<<<24576, 256, 0, stream>>>(x, mask, Wqkv, Wout, xb, mbits, Wqkv_t, Wout_t);
  gemm_qkv_kernel<<<768, 256, 0, stream>>>(xb, Wqkv_t, Qb, Kb, Vt);
  attn_kernel<<<1024, 256, 0, stream>>>(Qb, Kb, Vt, mbits, attnb);
  gemm_out_kernel<<<512, 256, 0, stream>>>(attnb, Wout_t, bout, out);
}